// Round 6
// baseline (739.103 us; speedup 1.0000x reference)
//
#include <hip/hip_runtime.h>
#include <math.h>

#define S 512
#define W 64
#define MODES 16
#define PAIRS 130816  // 512*511/2
#define INV_SQRT_N 0.04419417382415922f  // 1/sqrt(512)
#define TWO_PI_OVER_N 0.012271846303085130f  // 2*pi/512

// ---------------- one-time: transpose spec weights -> wmT[l][i][m][o] (float2)
__global__ __launch_bounds__(256) void k_prep(const float* __restrict__ specw,
                                              float* __restrict__ wmT) {
    int bi = blockIdx.x;  // 0..255 = l*64 + i
    int tid = threadIdx.x, o = tid & 63, tg = tid >> 6;
#pragma unroll
    for (int k = 0; k < 4; ++k) {
        int m = tg * 4 + k;
        float2 wv = *(const float2*)(specw + (((size_t)bi * 64 + o) * 16 + m) * 2);
        *(float2*)(wmT + (((size_t)bi * 16 + m) * 64 + o) * 2) = wv;
    }
}

// ---------------- rfft (ortho), first 16 modes only. block=(b,c), 256 thr.
// first!=0: layer-0 input is fc0(x) computed on the fly. Also zeroes vmax.
__global__ __launch_bounds__(256) void k_fft(const float* __restrict__ h,
                                             const float* __restrict__ x,
                                             const float* __restrict__ fc0w,
                                             const float* __restrict__ fc0b,
                                             float* __restrict__ Xf,
                                             unsigned* __restrict__ vmax,
                                             int first) {
    int b = blockIdx.x >> 6, ch = blockIdx.x & 63;
    int tid = threadIdx.x;  // t = tid and tid+256
    if (blockIdx.x == 0 && tid < 2) vmax[tid] = 0u;  // consumed 2 dispatches later
    float v0, v1;
    if (first) {
        float w0 = fc0w[ch], w1 = fc0w[64 + ch], bb = fc0b[ch];
        const float* xb = x + (size_t)b * S * 2;
        v0 = xb[2 * tid] * w0 + xb[2 * tid + 1] * w1 + bb;
        v1 = xb[2 * (tid + 256)] * w0 + xb[2 * (tid + 256) + 1] * w1 + bb;
    } else {
        const float* hp = h + (b * W + ch) * S;
        v0 = hp[tid]; v1 = hp[tid + 256];
    }
    // sincos recurrence: seed theta = 2*pi*t/N, rotate for m = 0..15.
    float c1, s1;
    sincosf(TWO_PI_OVER_N * (float)tid, &s1, &c1);
    float cm = 1.f, sm = 0.f;
    float ap = v0 + v1, am = v0 - v1;  // e^{-i pi m} = (-1)^m
    float re[MODES], im[MODES];
#pragma unroll
    for (int m = 0; m < MODES; ++m) {
        float a = (m & 1) ? am : ap;
        re[m] = a * cm;
        im[m] = -a * sm;
        float nc = cm * c1 - sm * s1;
        float ns = sm * c1 + cm * s1;
        cm = nc; sm = ns;
    }
    __shared__ float part[4][32];
    int lane = tid & 63, wv = tid >> 6;
#pragma unroll
    for (int m = 0; m < MODES; ++m) {
        float r = re[m], ii = im[m];
        for (int off = 32; off; off >>= 1) {
            r += __shfl_down(r, off);
            ii += __shfl_down(ii, off);
        }
        if (lane == 0) { part[wv][2 * m] = r; part[wv][2 * m + 1] = ii; }
    }
    __syncthreads();
    if (tid < 32) {
        float s = part[0][tid] + part[1][tid] + part[2][tid] + part[3][tid];
        Xf[(b * W + ch) * 32 + tid] = s * INV_SQRT_N;
    }
}

// ---------------- fused mix + irfft + conv + pairwise (512 blocks).
// Each 32x32 pair-tile block recomputes its 64 rows of pT/aT in LDS
// (bit-identical across blocks: same code, same inputs). Diagonal blocks
// (i0==j0) also write aT/pT to global for k_mpf.
__global__ __launch_bounds__(256) void k_map(const float* __restrict__ Xf,
                                             const float* __restrict__ wmT,
                                             const float* __restrict__ h,
                                             const float* __restrict__ x,
                                             const float* __restrict__ fc0w,
                                             const float* __restrict__ fc0b,
                                             const float* __restrict__ convw,
                                             const float* __restrict__ convb,
                                             float* __restrict__ aT,
                                             float* __restrict__ pT,
                                             float* __restrict__ vr,
                                             float* __restrict__ uxm,
                                             unsigned* __restrict__ vmax,
                                             int l, int first) {
    int blk = blockIdx.x;
    int b = blk >> 8;
    int rest = blk & 255;
    int i0 = (rest & 15) * 32, j0 = (rest >> 4) * 32;
    int tid = threadIdx.x;
    int o = tid & 63, og = tid >> 6;  // channel lane, wave index
    __shared__ __align__(16) float Ys[64 * 34];       // 8704 B
    __shared__ __align__(16) float hs[64][64];        // 16384 B; [c][r]
    __shared__ __align__(16) float PV[4 * 64 * 34];   // 34816 B; Xs aliases [0..2047]
    float* Pi = PV;
    float* Pj = PV + 2176;
    float* Vi = PV + 4352;
    float* Vj = PV + 6528;
    float* Xs = PV;  // alias: dead after mix phase, overwritten by irfft phase
    // ---- stage Xf and h-columns
    for (int idx = tid; idx < 2048; idx += 256) Xs[idx] = Xf[b * 2048 + idx];
    for (int idx = tid; idx < 4096; idx += 256) {
        int c = idx >> 6, r = idx & 63;
        int tr = (r < 32) ? (i0 + r) : (j0 + r - 32);
        if (first) {
            const float* xb = x + ((size_t)b * S + tr) * 2;
            hs[c][r] = xb[0] * fc0w[c] + xb[1] * fc0w[64 + c] + fc0b[c];
        } else {
            hs[c][r] = h[(b * W + c) * S + tr];
        }
    }
    __syncthreads();
    // ---- mix: thread (o, og) computes Y[o][m] for m = og*4..og*4+3
    {
        float ar[4] = {0.f, 0.f, 0.f, 0.f}, ai[4] = {0.f, 0.f, 0.f, 0.f};
        const float2* wp = (const float2*)wmT + ((size_t)(l * 1024) + og * 4) * 64 + o;
        for (int i = 0; i < 64; ++i) {
#pragma unroll
            for (int mm = 0; mm < 4; ++mm) {
                float2 wv = wp[(size_t)(i * 16 + mm) * 64];
                float2 xv = *(const float2*)&Xs[i * 32 + (og * 4 + mm) * 2];
                ar[mm] += xv.x * wv.x - xv.y * wv.y;
                ai[mm] += xv.x * wv.y + xv.y * wv.x;
            }
        }
#pragma unroll
        for (int mm = 0; mm < 4; ++mm) {
            float2 yv; yv.x = ar[mm]; yv.y = ai[mm];
            *(float2*)&Ys[o * 34 + (og * 4 + mm) * 2] = yv;
        }
    }
    __syncthreads();  // Xs reads done; Ys visible; PV may now be overwritten
    // ---- irfft + conv for 64 rows (r<32: i-rows, r>=32: j-rows)
    {
        float yr[MODES], yi[MODES];
#pragma unroll
        for (int m = 0; m < MODES; ++m) {
            float2 yv = *(const float2*)&Ys[o * 34 + 2 * m];
            yr[m] = yv.x; yi[m] = yv.y;
        }
        float4 wreg[16];
        const float4* wp4 = (const float4*)(convw + l * 4096 + o * 64);
#pragma unroll
        for (int q = 0; q < 16; ++q) wreg[q] = wp4[q];
        float bias = convb[l * W + o];
        bool diag = (i0 == j0);
        for (int k = 0; k < 16; ++k) {
            int r = og + 4 * k;
            int tr = (r < 32) ? (i0 + r) : (j0 + r - 32);
            float c1, s1;
            sincosf(TWO_PI_OVER_N * (float)tr, &s1, &c1);
            float cm = c1, sm = s1;
            float acc = yr[0];
#pragma unroll
            for (int m = 1; m < MODES; ++m) {
                acc += 2.0f * (yr[m] * cm - yi[m] * sm);
                float nc = cm * c1 - sm * s1;
                float ns = sm * c1 + cm * s1;
                cm = nc; sm = ns;
            }
            float av = acc * INV_SQRT_N;
            float pv = bias;
#pragma unroll
            for (int q = 0; q < 16; ++q) {
                float4 w4 = wreg[q];
                pv = fmaf(w4.x, hs[4 * q + 0][r], pv);
                pv = fmaf(w4.y, hs[4 * q + 1][r], pv);
                pv = fmaf(w4.z, hs[4 * q + 2][r], pv);
                pv = fmaf(w4.w, hs[4 * q + 3][r], pv);
            }
            if (r < 32) { Pi[o * 34 + r] = pv; Vi[o * 34 + r] = av; }
            else        { Pj[o * 34 + (r - 32)] = pv; Vj[o * 34 + (r - 32)] = av; }
            if (diag && r < 32) {
                aT[((size_t)b * S + tr) * W + o] = av;
                pT[((size_t)b * S + tr) * W + o] = pv;
            }
        }
    }
    __syncthreads();
    // ---- pairwise 32x32 tile (unchanged from validated k_pair)
    int tx = tid & 15, ty = tid >> 4;
    float ax[2][2] = {{0.f, 0.f}, {0.f, 0.f}};
    float av2[2][2] = {{0.f, 0.f}, {0.f, 0.f}};
    for (int c = 0; c < W; ++c) {
        float2 pi = *(const float2*)&Pi[c * 34 + 2 * tx];
        float2 pj = *(const float2*)&Pj[c * 34 + 2 * ty];
        float2 vi = *(const float2*)&Vi[c * 34 + 2 * tx];
        float2 vj = *(const float2*)&Vj[c * 34 + 2 * ty];
        float d;
        d = pi.x - pj.x; ax[0][0] = fmaf(d, d, ax[0][0]);
        d = pi.y - pj.x; ax[1][0] = fmaf(d, d, ax[1][0]);
        d = pi.x - pj.y; ax[0][1] = fmaf(d, d, ax[0][1]);
        d = pi.y - pj.y; ax[1][1] = fmaf(d, d, ax[1][1]);
        d = vi.x - vj.x; av2[0][0] = fmaf(d, d, av2[0][0]);
        d = vi.y - vj.x; av2[1][0] = fmaf(d, d, av2[1][0]);
        d = vi.x - vj.y; av2[0][1] = fmaf(d, d, av2[0][1]);
        d = vi.y - vj.y; av2[1][1] = fmaf(d, d, av2[1][1]);
    }
    float mx = 0.f;
#pragma unroll
    for (int jj = 0; jj < 2; ++jj) {
#pragma unroll
        for (int ii = 0; ii < 2; ++ii) {
            int i = i0 + 2 * tx + ii, j = j0 + 2 * ty + jj;
            float xr = sqrtf(ax[ii][jj]);
            float vv = sqrtf(av2[ii][jj]);
            vr[((size_t)b * S + j) * S + i] = vv;
            uxm[((size_t)b * S + j) * S + i] = expf(-xr);
            mx = fmaxf(mx, vv);
        }
    }
    __shared__ float mxs[4];
    for (int off = 32; off; off >>= 1) mx = fmaxf(mx, __shfl_xor(mx, off));
    if ((tid & 63) == 0) mxs[tid >> 6] = mx;
    __syncthreads();
    if (tid == 0) {
        float m = fmaxf(fmaxf(mxs[0], mxs[1]), fmaxf(mxs[2], mxs[3]));
        atomicMax(&vmax[b], __float_as_uint(m));
    }
}

// ---------------- fused mask + per-row projection + finalize (+ head at l==3).
__global__ __launch_bounds__(256) void k_mpf(const float* __restrict__ vr,
                                             const float* __restrict__ uxm,
                                             const unsigned* __restrict__ vmaxu,
                                             const float* __restrict__ aT,
                                             const float* __restrict__ pT,
                                             const float* __restrict__ vecs,
                                             float* __restrict__ h_std,
                                             const float* __restrict__ fc1w,
                                             const float* __restrict__ fc1b,
                                             const float* __restrict__ fc2w,
                                             const float* __restrict__ fc2b,
                                             float* __restrict__ out,
                                             int l, int do_relu, int do_head) {
    int b = blockIdx.x >> 9, q = blockIdx.x & 511;
    int tid = threadIdx.x, lane = tid & 63, wv = tid >> 6;
    __shared__ float wrow[S];
    __shared__ float SV[4][64], SX[4][64], TP[4][64];
    __shared__ float hrow[64];
    __shared__ int cnt4[4];
    const float* vrp = vr + ((size_t)b * S + q) * S;
    const float* uxp = uxm + ((size_t)b * S + q) * S;
    float vmax = __uint_as_float(vmaxu[b]);
    int mycnt = 0;
    {
        float2 v2 = *(const float2*)&vrp[2 * tid];
        float2 u2 = *(const float2*)&uxp[2 * tid];
        bool a0 = (v2.x / vmax) * u2.x > 0.1f;
        bool a1 = (v2.y / vmax) * u2.y > 0.1f;
        wrow[2 * tid] = a0 ? v2.x : 0.f;
        wrow[2 * tid + 1] = a1 ? v2.y : 0.f;
        mycnt = (a0 ? 1 : 0) + (a1 ? 1 : 0);
    }
    for (int o = 32; o; o >>= 1) mycnt += __shfl_down(mycnt, o);
    if (lane == 0) cnt4[wv] = mycnt;
    __syncthreads();
    float A = (float)(cnt4[0] + cnt4[1] + cnt4[2] + cnt4[3]);
    float svp = 0.f, sxp = 0.f, tp = 0.f;
    const float* aTb = aT + (size_t)b * S * W;
    const float* pTb = pT + (size_t)b * S * W;
    const float* Rb = vecs + (size_t)((l * 2 + b) * W + lane) * PAIRS;
    int triq = q * 511 - ((q * (q - 1)) >> 1);
    for (int k = 0; k < 128; ++k) {
        int p = (wv << 7) + k;
        float w = wrow[p];
        if (w != 0.f) {  // wave-uniform branch
            svp += aTb[p * W + lane];
            sxp += pTb[p * W + lane];
            int idx; float sgn;
            if (p < q) { idx = p * 511 - ((p * (p - 1)) >> 1) + (q - p - 1); sgn = 1.f; }
            else       { idx = triq + (p - q - 1); sgn = -1.f; }
            tp = fmaf(sgn * w, Rb[idx], tp);
        }
    }
    SV[wv][lane] = svp; SX[wv][lane] = sxp; TP[wv][lane] = tp;
    __syncthreads();
    if (wv == 0) {
        float sv = SV[0][lane] + SV[1][lane] + SV[2][lane] + SV[3][lane];
        float sx = SX[0][lane] + SX[1][lane] + SX[2][lane] + SX[3][lane];
        float T  = TP[0][lane] + TP[1][lane] + TP[2][lane] + TP[3][lane];
        float vj = aTb[q * W + lane], xj = pTb[q * W + lane];
        float vnew = vj + 0.5f * (A * vj - sv) + T;
        float accx = 0.5f * (A * xj + sx);
        float xnew = (xj + accx) / (A + 1.0f) + vnew;
        if (do_relu) xnew = fmaxf(xnew, 0.0f);
        if (!do_head) h_std[((size_t)b * W + lane) * S + q] = xnew;
        else hrow[lane] = xnew;
    }
    if (do_head) {
        __syncthreads();
        if (wv == 0) {
            float a0 = fc1b[lane], a1 = fc1b[lane + 64];
            for (int cc = 0; cc < W; ++cc) {
                float hv = hrow[cc];
                a0 = fmaf(hv, fc1w[cc * 128 + lane], a0);
                a1 = fmaf(hv, fc1w[cc * 128 + lane + 64], a1);
            }
            a0 = fmaxf(a0, 0.f); a1 = fmaxf(a1, 0.f);
            float p = a0 * fc2w[lane] + a1 * fc2w[lane + 64];
            for (int off = 32; off; off >>= 1) p += __shfl_down(p, off);
            if (lane == 0) out[b * S + q] = p + fc2b[0];
        }
    }
}

extern "C" void kernel_launch(void* const* d_in, const int* in_sizes, int n_in,
                              void* d_out, int out_size, void* d_ws, size_t ws_size,
                              hipStream_t stream) {
    const float* x = (const float*)d_in[0];
    const float* vecs = (const float*)d_in[2];
    const float* fc0w = (const float*)d_in[3];
    const float* fc0b = (const float*)d_in[4];
    const float* specw = (const float*)d_in[5];
    const float* convw = (const float*)d_in[6];
    const float* convb = (const float*)d_in[7];
    const float* fc1w = (const float*)d_in[8];
    const float* fc1b = (const float*)d_in[9];
    const float* fc2w = (const float*)d_in[10];
    const float* fc2b = (const float*)d_in[11];
    float* out = (float*)d_out;

    char* ws = (char*)d_ws;
    unsigned* vmax = (unsigned*)ws;                   // 2 x u32 (float bits)
    float* h_std = (float*)(ws + 256);                // 2*64*512
    float* aT = h_std + 65536;                        // 2*512*64
    float* pT = aT + 65536;                           // 2*512*64
    float* Xf = pT + 65536;                           // 2*64*32
    float* wmT = Xf + 4096;                           // 4*64*16*64*2 = 524288
    float* vrbuf = wmT + 524288;                      // 2*512*512
    float* uxbuf = vrbuf + 524288;                    // 2*512*512

    k_prep<<<256, 256, 0, stream>>>(specw, wmT);
    for (int l = 0; l < 4; ++l) {
        int first = (l == 0) ? 1 : 0;
        k_fft<<<128, 256, 0, stream>>>(h_std, x, fc0w, fc0b, Xf, vmax, first);
        k_map<<<512, 256, 0, stream>>>(Xf, wmT, h_std, x, fc0w, fc0b,
                                       convw, convb, aT, pT, vrbuf, uxbuf,
                                       vmax, l, first);
        k_mpf<<<1024, 256, 0, stream>>>(vrbuf, uxbuf, vmax, aT, pT, vecs,
                                        h_std, fc1w, fc1b, fc2w, fc2b, out,
                                        l, (l < 3) ? 1 : 0, (l == 3) ? 1 : 0);
    }
}

// Round 7
// 648.241 us; speedup vs baseline: 1.1402x; 1.1402x over previous
//
#include <hip/hip_runtime.h>
#include <math.h>

#define S 512
#define W 64
#define MODES 16
#define PAIRS 130816  // 512*511/2
#define INV_SQRT_N 0.04419417382415922f  // 1/sqrt(512)
#define TWO_PI_OVER_N 0.012271846303085130f  // 2*pi/512

// ---------------- rfft (ortho), first 16 modes only. block=(b,c), 256 thr.
// first!=0: layer-0 input is fc0(x) computed on the fly (h never materialized).
__global__ __launch_bounds__(256) void k_fft(const float* __restrict__ h,
                                             const float* __restrict__ x,
                                             const float* __restrict__ fc0w,
                                             const float* __restrict__ fc0b,
                                             float* __restrict__ Xf, int first) {
    int b = blockIdx.x >> 6, ch = blockIdx.x & 63;
    int tid = threadIdx.x;  // t = tid and tid+256
    float v0, v1;
    if (first) {
        float w0 = fc0w[ch], w1 = fc0w[64 + ch], bb = fc0b[ch];
        const float* xb = x + (size_t)b * S * 2;
        v0 = xb[2 * tid] * w0 + xb[2 * tid + 1] * w1 + bb;
        v1 = xb[2 * (tid + 256)] * w0 + xb[2 * (tid + 256) + 1] * w1 + bb;
    } else {
        const float* hp = h + (b * W + ch) * S;
        v0 = hp[tid]; v1 = hp[tid + 256];
    }
    // sincos recurrence: seed theta = 2*pi*t/N, rotate for m = 0..15.
    float c1, s1;
    sincosf(TWO_PI_OVER_N * (float)tid, &s1, &c1);
    float cm = 1.f, sm = 0.f;
    float ap = v0 + v1, am = v0 - v1;  // e^{-i pi m} = (-1)^m
    float re[MODES], im[MODES];
#pragma unroll
    for (int m = 0; m < MODES; ++m) {
        float a = (m & 1) ? am : ap;
        re[m] = a * cm;
        im[m] = -a * sm;
        float nc = cm * c1 - sm * s1;
        float ns = sm * c1 + cm * s1;
        cm = nc; sm = ns;
    }
    __shared__ float part[4][32];
    int lane = tid & 63, wv = tid >> 6;
#pragma unroll
    for (int m = 0; m < MODES; ++m) {
        float r = re[m], ii = im[m];
        for (int off = 32; off; off >>= 1) {
            r += __shfl_down(r, off);
            ii += __shfl_down(ii, off);
        }
        if (lane == 0) { part[wv][2 * m] = r; part[wv][2 * m + 1] = ii; }
    }
    __syncthreads();
    if (tid < 32) {
        float s = part[0][tid] + part[1][tid] + part[2][tid] + part[3][tid];
        Xf[(b * W + ch) * 32 + tid] = s * INV_SQRT_N;
    }
}

// ---------------- complex channel mix: Y[b,o,m] = sum_i Xf[b,i,m]*wm[i,o,m]
__global__ __launch_bounds__(256) void k_mix(const float* __restrict__ Xf,
                                             const float* __restrict__ specw,
                                             float* __restrict__ Y, int l) {
    int b = blockIdx.x >> 6, o = blockIdx.x & 63;
    int tid = threadIdx.x, m = tid & 15, ip = tid >> 4;
    __shared__ float Xs[2048];
    for (int idx = tid; idx < 2048; idx += 256) Xs[idx] = Xf[b * 2048 + idx];
    __syncthreads();
    float ar = 0.f, ai = 0.f;
#pragma unroll
    for (int q = 0; q < 4; ++q) {
        int i = ip * 4 + q;
        const float* wp = specw + (size_t)(((l * W + i) * W + o) * MODES + m) * 2;
        float wr = wp[0], wi = wp[1];
        float xr = Xs[i * 32 + 2 * m], xi = Xs[i * 32 + 2 * m + 1];
        ar += xr * wr - xi * wi;
        ai += xr * wi + xi * wr;
    }
    __shared__ float redr[16][17], redi[16][17];
    redr[ip][m] = ar; redi[ip][m] = ai;
    __syncthreads();
    if (tid < 16) {
        float sr = 0.f, si = 0.f;
        for (int p = 0; p < 16; ++p) { sr += redr[p][tid]; si += redi[p][tid]; }
        Y[(b * W + o) * 32 + 2 * tid] = sr;
        Y[(b * W + o) * 32 + 2 * tid + 1] = si;
    }
}

// ---------------- fused irfft (ortho, 16 modes) + pointwise conv.
// 256 blocks = b(2) x 128 t-tiles of 4. thread: o = tid&63, t = t0 + (tid>>6).
__global__ __launch_bounds__(256) void k_ac(const float* __restrict__ Y,
                                            const float* __restrict__ h,
                                            const float* __restrict__ x,
                                            const float* __restrict__ fc0w,
                                            const float* __restrict__ fc0b,
                                            const float* __restrict__ convw,
                                            const float* __restrict__ convb,
                                            float* __restrict__ aT,
                                            float* __restrict__ pT,
                                            unsigned* __restrict__ vmax,
                                            int l, int first) {
    int blk = blockIdx.x;
    int b = blk >> 7, t0 = (blk & 127) * 4;
    int tid = threadIdx.x;
    int o = tid & 63, tg = tid >> 6;
    if (blk == 0 && tid < 2) vmax[tid] = 0u;  // zero v_r_max for this layer
    __shared__ float hs[64 * 5];
    {
        int r = tid >> 2, t = tid & 3;
        if (first) {
            const float* xb = x + ((size_t)b * S + t0 + t) * 2;
            hs[r * 5 + t] = xb[0] * fc0w[r] + xb[1] * fc0w[64 + r] + fc0b[r];
        } else {
            hs[r * 5 + t] = h[(b * W + r) * S + t0 + t];
        }
    }
    // Y modes for this thread's channel: 32 consecutive floats, own 128B segment.
    float yr[MODES], yi[MODES];
    const float4* yp = (const float4*)(Y + b * 2048 + o * 32);
#pragma unroll
    for (int q = 0; q < 8; ++q) {
        float4 y4 = yp[q];
        yr[2 * q] = y4.x; yi[2 * q] = y4.y;
        yr[2 * q + 1] = y4.z; yi[2 * q + 1] = y4.w;
    }
    int t = t0 + tg;
    // sincos recurrence over m (seed theta = 2*pi*t/N).
    float c1, s1;
    sincosf(TWO_PI_OVER_N * (float)t, &s1, &c1);
    float cm = c1, sm = s1;
    float acc = yr[0];
#pragma unroll
    for (int m = 1; m < MODES; ++m) {
        acc += 2.0f * (yr[m] * cm - yi[m] * sm);
        float nc = cm * c1 - sm * s1;
        float ns = sm * c1 + cm * s1;
        cm = nc; sm = ns;
    }
    aT[((size_t)b * S + t) * W + o] = acc * INV_SQRT_N;
    // ---- conv: own weight row, 64 consecutive floats via float4
    __syncthreads();
    float pacc = convb[l * W + o];
    const float4* wp = (const float4*)(convw + l * 4096 + o * 64);
#pragma unroll
    for (int i4 = 0; i4 < 16; ++i4) {
        float4 w4 = wp[i4];
        pacc = fmaf(w4.x, hs[(4 * i4 + 0) * 5 + tg], pacc);
        pacc = fmaf(w4.y, hs[(4 * i4 + 1) * 5 + tg], pacc);
        pacc = fmaf(w4.z, hs[(4 * i4 + 2) * 5 + tg], pacc);
        pacc = fmaf(w4.w, hs[(4 * i4 + 3) * 5 + tg], pacc);
    }
    pT[((size_t)b * S + t) * W + o] = pacc;
}

// ---------------- pairwise: v_r[b,j,i], u_x[b,j,i]=exp(-x_r), atomicMax v_r_max
__global__ __launch_bounds__(256) void k_pair(const float* __restrict__ pT,
                                              const float* __restrict__ aT,
                                              float* __restrict__ vr,
                                              float* __restrict__ uxm,
                                              unsigned* __restrict__ vmax) {
    int blk = blockIdx.x;
    int b = blk >> 8;
    int rest = blk & 255;
    int i0 = (rest & 15) * 32, j0 = (rest >> 4) * 32;
    int tid = threadIdx.x;
    int tx = tid & 15, ty = tid >> 4;
    __shared__ __align__(16) float Pi[64 * 34];
    __shared__ __align__(16) float Pj[64 * 34];
    __shared__ __align__(16) float Vi[64 * 34];
    __shared__ __align__(16) float Vj[64 * 34];
    for (int idx = tid; idx < 2048; idx += 256) {
        int k = idx >> 6, c = idx & 63;
        Pi[c * 34 + k] = pT[(b * S + i0 + k) * W + c];
        Pj[c * 34 + k] = pT[(b * S + j0 + k) * W + c];
        Vi[c * 34 + k] = aT[(b * S + i0 + k) * W + c];
        Vj[c * 34 + k] = aT[(b * S + j0 + k) * W + c];
    }
    __syncthreads();
    float ax[2][2] = {{0.f, 0.f}, {0.f, 0.f}};
    float av[2][2] = {{0.f, 0.f}, {0.f, 0.f}};
    for (int c = 0; c < W; ++c) {
        float2 pi = *(const float2*)&Pi[c * 34 + 2 * tx];
        float2 pj = *(const float2*)&Pj[c * 34 + 2 * ty];
        float2 vi = *(const float2*)&Vi[c * 34 + 2 * tx];
        float2 vj = *(const float2*)&Vj[c * 34 + 2 * ty];
        float d;
        d = pi.x - pj.x; ax[0][0] = fmaf(d, d, ax[0][0]);
        d = pi.y - pj.x; ax[1][0] = fmaf(d, d, ax[1][0]);
        d = pi.x - pj.y; ax[0][1] = fmaf(d, d, ax[0][1]);
        d = pi.y - pj.y; ax[1][1] = fmaf(d, d, ax[1][1]);
        d = vi.x - vj.x; av[0][0] = fmaf(d, d, av[0][0]);
        d = vi.y - vj.x; av[1][0] = fmaf(d, d, av[1][0]);
        d = vi.x - vj.y; av[0][1] = fmaf(d, d, av[0][1]);
        d = vi.y - vj.y; av[1][1] = fmaf(d, d, av[1][1]);
    }
    float mx = 0.f;
#pragma unroll
    for (int jj = 0; jj < 2; ++jj) {
#pragma unroll
        for (int ii = 0; ii < 2; ++ii) {
            int i = i0 + 2 * tx + ii, j = j0 + 2 * ty + jj;
            float xr = sqrtf(ax[ii][jj]);
            float vv = sqrtf(av[ii][jj]);
            vr[((size_t)b * S + j) * S + i] = vv;
            uxm[((size_t)b * S + j) * S + i] = expf(-xr);
            mx = fmaxf(mx, vv);
        }
    }
    __shared__ float mxs[4];
    for (int off = 32; off; off >>= 1) mx = fmaxf(mx, __shfl_xor(mx, off));
    if ((tid & 63) == 0) mxs[tid >> 6] = mx;
    __syncthreads();
    if (tid == 0) {
        float m = fmaxf(fmaxf(mxs[0], mxs[1]), fmaxf(mxs[2], mxs[3]));
        atomicMax(&vmax[b], __float_as_uint(m));
    }
}

// ---------------- fused mask + per-row projection + finalize (+ head at l==3).
// Ballot-compressed sweep: wave wv owns p in [wv*128, wv*128+128); lane L holds
// p = seg+L and p = seg+64+L in registers; actives iterated via ffs over the
// ballot masks (ascending p -> summation order identical to the serial loop).
__global__ __launch_bounds__(256) void k_mpf(const float* __restrict__ vr,
                                             const float* __restrict__ uxm,
                                             const unsigned* __restrict__ vmaxu,
                                             const float* __restrict__ aT,
                                             const float* __restrict__ pT,
                                             const float* __restrict__ vecs,
                                             float* __restrict__ h_std,
                                             const float* __restrict__ fc1w,
                                             const float* __restrict__ fc1b,
                                             const float* __restrict__ fc2w,
                                             const float* __restrict__ fc2b,
                                             float* __restrict__ out,
                                             int l, int do_relu, int do_head) {
    int b = blockIdx.x >> 9, q = blockIdx.x & 511;
    int tid = threadIdx.x, lane = tid & 63, wv = tid >> 6;
    __shared__ float SV[4][64], SX[4][64], TP[4][64];
    __shared__ float hrow[64];
    __shared__ int cnt4[4];
    const float* vrp = vr + ((size_t)b * S + q) * S;
    const float* uxp = uxm + ((size_t)b * S + q) * S;
    float vmax = __uint_as_float(vmaxu[b]);
    int seg = wv << 7;
    float va = vrp[seg + lane], vb = vrp[seg + 64 + lane];
    float ua = uxp[seg + lane], ub = uxp[seg + 64 + lane];
    bool actA = (va / vmax) * ua > 0.1f;   // exact reference expression
    bool actB = (vb / vmax) * ub > 0.1f;
    unsigned long long mA = __ballot(actA);
    unsigned long long mB = __ballot(actB);
    if (lane == 0) cnt4[wv] = __popcll(mA) + __popcll(mB);
    float wAv = actA ? va : 0.f;  // shfl broadcast sources
    float wBv = actB ? vb : 0.f;
    float svp = 0.f, sxp = 0.f, tp = 0.f;
    const float* aTb = aT + (size_t)b * S * W;
    const float* pTb = pT + (size_t)b * S * W;
    const float* Rb = vecs + (size_t)((l * 2 + b) * W + lane) * PAIRS;
    int triq = q * 511 - ((q * (q - 1)) >> 1);
#pragma unroll
    for (int half = 0; half < 2; ++half) {
        unsigned long long m = half ? mB : mA;
        int base = seg + (half ? 64 : 0);
        float wsrc = half ? wBv : wAv;
        while (m) {
            int bit = (int)__ffsll(m) - 1;
            m &= m - 1;
            int p = base + bit;
            float w = __shfl(wsrc, bit);
            svp += aTb[p * W + lane];
            sxp += pTb[p * W + lane];
            int idx; float sgn;
            if (p < q) { idx = p * 511 - ((p * (p - 1)) >> 1) + (q - p - 1); sgn = 1.f; }
            else       { idx = triq + (p - q - 1); sgn = -1.f; }
            tp = fmaf(sgn * w, Rb[idx], tp);
        }
    }
    SV[wv][lane] = svp; SX[wv][lane] = sxp; TP[wv][lane] = tp;
    __syncthreads();
    if (wv == 0) {
        float A = (float)(cnt4[0] + cnt4[1] + cnt4[2] + cnt4[3]);
        float sv = SV[0][lane] + SV[1][lane] + SV[2][lane] + SV[3][lane];
        float sx = SX[0][lane] + SX[1][lane] + SX[2][lane] + SX[3][lane];
        float T  = TP[0][lane] + TP[1][lane] + TP[2][lane] + TP[3][lane];
        float vj = aTb[q * W + lane], xj = pTb[q * W + lane];
        float vnew = vj + 0.5f * (A * vj - sv) + T;
        float accx = 0.5f * (A * xj + sx);
        float xnew = (xj + accx) / (A + 1.0f) + vnew;
        if (do_relu) xnew = fmaxf(xnew, 0.0f);
        if (!do_head) h_std[((size_t)b * W + lane) * S + q] = xnew;
        else hrow[lane] = xnew;
    }
    if (do_head) {
        __syncthreads();
        if (wv == 0) {
            float a0 = fc1b[lane], a1 = fc1b[lane + 64];
            for (int cc = 0; cc < W; ++cc) {
                float hv = hrow[cc];
                a0 = fmaf(hv, fc1w[cc * 128 + lane], a0);
                a1 = fmaf(hv, fc1w[cc * 128 + lane + 64], a1);
            }
            a0 = fmaxf(a0, 0.f); a1 = fmaxf(a1, 0.f);
            float p = a0 * fc2w[lane] + a1 * fc2w[lane + 64];
            for (int off = 32; off; off >>= 1) p += __shfl_down(p, off);
            if (lane == 0) out[b * S + q] = p + fc2b[0];
        }
    }
}

extern "C" void kernel_launch(void* const* d_in, const int* in_sizes, int n_in,
                              void* d_out, int out_size, void* d_ws, size_t ws_size,
                              hipStream_t stream) {
    const float* x = (const float*)d_in[0];
    const float* vecs = (const float*)d_in[2];
    const float* fc0w = (const float*)d_in[3];
    const float* fc0b = (const float*)d_in[4];
    const float* specw = (const float*)d_in[5];
    const float* convw = (const float*)d_in[6];
    const float* convb = (const float*)d_in[7];
    const float* fc1w = (const float*)d_in[8];
    const float* fc1b = (const float*)d_in[9];
    const float* fc2w = (const float*)d_in[10];
    const float* fc2b = (const float*)d_in[11];
    float* out = (float*)d_out;

    char* ws = (char*)d_ws;
    unsigned* vmax = (unsigned*)ws;                   // 2 x u32 (float bits)
    float* h_std = (float*)(ws + 256);                // 2*64*512
    float* aT = h_std + 65536;                        // 2*512*64
    float* pT = aT + 65536;                           // 2*512*64
    float* Xf = pT + 65536;                           // 2*64*32
    float* Yb = Xf + 4096;                            // 2*64*32
    float* vrbuf = Yb + 4096;                         // 2*512*512
    float* uxbuf = vrbuf + 524288;                    // 2*512*512

    for (int l = 0; l < 4; ++l) {
        int first = (l == 0) ? 1 : 0;
        k_fft<<<128, 256, 0, stream>>>(h_std, x, fc0w, fc0b, Xf, first);
        k_mix<<<128, 256, 0, stream>>>(Xf, specw, Yb, l);
        k_ac<<<256, 256, 0, stream>>>(Yb, h_std, x, fc0w, fc0b, convw, convb,
                                      aT, pT, vmax, l, first);
        k_pair<<<512, 256, 0, stream>>>(pT, aT, vrbuf, uxbuf, vmax);
        k_mpf<<<1024, 256, 0, stream>>>(vrbuf, uxbuf, vmax, aT, pT, vecs,
                                        h_std, fc1w, fc1b, fc2w, fc2b, out,
                                        l, (l < 3) ? 1 : 0, (l == 3) ? 1 : 0);
    }
}